// Round 1
// baseline (933.796 us; speedup 1.0000x reference)
//
#include <hip/hip_runtime.h>
#include <cmath>

#define SEQ 1600
#define NB  1024
#define H   12
#define PP  8
#define CH  25   // 64 lanes * 25 = 1600

// ---------------- BN stats (analytic over the rank-1 projection) ----------------
__global__ __launch_bounds__(256) void k_stats1(const float* __restrict__ x,
                                                float* __restrict__ pS,
                                                float* __restrict__ pQ) {
    int l = blockIdx.x * 256 + threadIdx.x;
    if (l >= SEQ) return;
    int b0 = blockIdx.y * 64;
    float s = 0.f, q = 0.f;
    for (int b = 0; b < 64; ++b) {
        float v = x[(size_t)(b0 + b) * SEQ + l];
        s += v; q += v * v;
    }
    pS[blockIdx.y * SEQ + l] = s;
    pQ[blockIdx.y * SEQ + l] = q;
}

__global__ __launch_bounds__(256) void k_stats2(const float* __restrict__ pS,
                                                const float* __restrict__ pQ,
                                                const float* __restrict__ w1,
                                                const float* __restrict__ b1,
                                                const float* __restrict__ gam,
                                                const float* __restrict__ bet,
                                                float* __restrict__ scale,
                                                float* __restrict__ shift) {
    int l = blockIdx.x * 256 + threadIdx.x;
    if (l >= SEQ) return;
    float wm = 0, wq = 0, wb = 0, bm = 0, bq = 0;
    for (int h = 0; h < H; h++) {
        float w = w1[h], b = b1[h];
        wm += w; wq += w * w; wb += w * b; bm += b; bq += b * b;
    }
    const float inv = 1.f / 12.f;
    wm *= inv; wq *= inv; wb *= inv; bm *= inv; bq *= inv;
    float s = 0, q = 0;
    for (int k = 0; k < 16; k++) { s += pS[k * SEQ + l]; q += pQ[k * SEQ + l]; }
    float ex = s * (1.f / NB), exx = q * (1.f / NB);
    float mean = ex * wm + bm;                       // E_{b,h}[x w + b]
    float e2   = exx * wq + 2.f * ex * wb + bq;      // E[(xw+b)^2]
    float var  = e2 - mean * mean;                   // biased
    float sc   = gam[l] * rsqrtf(var + 1e-5f);
    scale[l] = sc;
    shift[l] = bet[l] - mean * sc;
}

// ---------------- cross-lane carry scan: s_i = A*s_{i-1} + e_i, A = lam_bar^25 ----------------
__device__ __forceinline__ void scan_carry(float* sr, float* si,
                                           const float* acr, const float* aci, int lane) {
    float wr[PP], wi[PP];
#pragma unroll
    for (int p = 0; p < PP; p++) { wr[p] = acr[p]; wi[p] = aci[p]; }
#pragma unroll
    for (int d = 1; d < 64; d <<= 1) {
#pragma unroll
        for (int p = 0; p < PP; p++) {
            float fr = __shfl_up(sr[p], (unsigned)d, 64);
            float fi = __shfl_up(si[p], (unsigned)d, 64);
            if (lane >= d) {
                sr[p] += wr[p] * fr - wi[p] * fi;
                si[p] += wr[p] * fi + wi[p] * fr;
            }
        }
#pragma unroll
        for (int p = 0; p < PP; p++) {  // w <- w^2
            float t = wr[p] * wr[p] - wi[p] * wi[p];
            wi[p] = 2.f * wr[p] * wi[p];
            wr[p] = t;
        }
    }
    // exclusive: carry_i = inclusive_{i-1}; lane 0 -> 0
#pragma unroll
    for (int p = 0; p < PP; p++) {
        float cr = __shfl_up(sr[p], 1u, 64);
        float ci = __shfl_up(si[p], 1u, 64);
        sr[p] = (lane > 0) ? cr : 0.f;
        si[p] = (lane > 0) ? ci : 0.f;
    }
}

// ---------------- fused pipeline: 1 wave per batch element ----------------
__global__ __launch_bounds__(256) void k_main(
    const float* __restrict__ x,
    const float* __restrict__ l1w, const float* __restrict__ l1b,
    const float* __restrict__ l2w, const float* __restrict__ l2b,
    const float* __restrict__ lamr, const float* __restrict__ lami,
    const float* __restrict__ bre, const float* __restrict__ bim,
    const float* __restrict__ cre, const float* __restrict__ cim,
    const float* __restrict__ dv,  const float* __restrict__ lstep,
    const float* __restrict__ g_scale, const float* __restrict__ g_shift,
    float* __restrict__ out) {
    __shared__ float xl[4][SEQ];        // per-wave input rows
    __shared__ float scl[SEQ], shl[SEQ];
    __shared__ float po[4][SEQ];        // per-wave output staging (partial -> fixed)
    __shared__ float4 bbv1[H * 4], bbv2[H * 4], c0v[H * 4], c1v[H * 4];
    __shared__ float lb0r[PP], lb0i[PP], lb1r[PP], lb1i[PP], lb2r[PP], lb2i[PP];
    __shared__ float ac0r[PP], ac0i[PP], ac1r[PP], ac1i[PP], ac2r[PP], ac2i[PP];
    __shared__ float A0r[PP], A0i[PP], B0r[PP], B0i[PP], C0r[PP], C0i[PP];
    __shared__ float A1r[PP], A1i[PP], B1r[PP], B1i[PP], A2r[PP], A2i[PP], B2r[PP], B2i[PP];
    __shared__ float cwr[PP], cwi[PP];
    __shared__ float w1s[H], b1s[H], d0s[H], d1s[H], dws[H];
    __shared__ float b2s;

    const int tid = threadIdx.x;

    // ---- preamble: derived parameters ----
    if (tid < H) {
        w1s[tid] = l1w[tid]; b1s[tid] = l1b[tid];
        d0s[tid] = dv[tid];  d1s[tid] = dv[H + tid];
        dws[tid] = l2w[tid] * dv[2 * H + tid];
    }
    if (tid == 0) b2s = l2b[0];
    for (int i = tid; i < 48; i += 256) {   // C matrices for layers 0,1 as float4 (re,im,re,im)
        int h = i >> 2, k = i & 3, p0 = 2 * k, p1 = 2 * k + 1;
        c0v[i] = make_float4(cre[h * PP + p0], cim[h * PP + p0], cre[h * PP + p1], cim[h * PP + p1]);
        c1v[i] = make_float4(cre[96 + h * PP + p0], cim[96 + h * PP + p0],
                             cre[96 + h * PP + p1], cim[96 + h * PP + p1]);
    }
    if (tid < 24) {
        int L = tid >> 3, p = tid & 7;
        float stp = expf(lstep[L * PP + p]);
        float lr = lamr[L * PP + p], li = lami[L * PP + p];
        float er = expf(lr * stp);
        float lbr = er * cosf(li * stp), lbi = er * sinf(li * stp);   // lam_bar
        // lam_bar^25 by square-multiply
        float rr = 1.f, ri = 0.f, br = lbr, bi = lbi;
        int e = CH;
        while (e) {
            if (e & 1) { float t = rr * br - ri * bi; ri = rr * bi + ri * br; rr = t; }
            e >>= 1;
            if (e) { float t = br * br - bi * bi; bi = 2.f * br * bi; br = t; }
        }
        // f = (lam_bar - 1)/lam
        float den = lr * lr + li * li;
        float fr = ((lbr - 1.f) * lr + lbi * li) / den;
        float fi = (lbi * lr - (lbr - 1.f) * li) / den;
        float sAr = 0, sAi = 0, sBr = 0, sBi = 0, sCr = 0, sCi = 0;
        for (int h = 0; h < H; h++) {
            float brr = bre[L * 96 + p * H + h], bii = bim[L * 96 + p * H + h];
            float vr = fr * brr - fi * bii, vi = fr * bii + fi * brr;  // b_bar[p,h]
            float w = l1w[h], bb = l1b[h];
            sAr += w * vr; sAi += w * vi; sBr += bb * vr; sBi += bb * vi; sCr += vr; sCi += vi;
            int fidx = h * 16 + (p >> 1) * 4 + (p & 1) * 2;
            if (L == 1)      { ((float*)bbv1)[fidx] = vr; ((float*)bbv1)[fidx + 1] = vi; }
            else if (L == 2) { ((float*)bbv2)[fidx] = vr; ((float*)bbv2)[fidx + 1] = vi; }
        }
        if (L == 0) {
            lb0r[p] = lbr; lb0i[p] = lbi; ac0r[p] = rr; ac0i[p] = ri;
            A0r[p] = sAr; A0i[p] = sAi; B0r[p] = sBr; B0i[p] = sBi; C0r[p] = sCr; C0i[p] = sCi;
        } else if (L == 1) {
            lb1r[p] = lbr; lb1i[p] = lbi; ac1r[p] = rr; ac1i[p] = ri;
            A1r[p] = sAr; A1i[p] = sAi; B1r[p] = sBr; B1i[p] = sBi;
        } else {
            lb2r[p] = lbr; lb2i[p] = lbi; ac2r[p] = rr; ac2i[p] = ri;
            A2r[p] = sAr; A2i[p] = sAi; B2r[p] = sBr; B2i[p] = sBi;
            float swr = 0, swi = 0;
            for (int hh = 0; hh < H; hh++) {
                float wv = l2w[hh];
                swr += wv * cre[192 + hh * PP + p];
                swi += wv * cim[192 + hh * PP + p];
            }
            cwr[p] = swr; cwi[p] = swi;   // cw = sum_h w2[h] * C2[h,p]
        }
    }
    for (int i = tid; i < SEQ; i += 256) { scl[i] = g_scale[i]; shl[i] = g_shift[i]; }
    const int b0 = blockIdx.x * 4;
    for (int i = tid; i < 4 * SEQ; i += 256)
        ((float*)xl)[i] = x[(size_t)b0 * SEQ + i];   // coalesced: w*SEQ+l == i
    __syncthreads();

    const int wv = tid >> 6, lane = tid & 63;
    const int b = b0 + wv;
    const float* __restrict__ xw = xl[wv];
    float* __restrict__ pw = po[wv];
    const int l0 = lane * CH;

    float s0r[PP], s0i[PP], s1r[PP], s1i[PP], s2r[PP], s2i[PP];
    float car0r[PP], car0i[PP], car1r[PP], car1i[PP];

    // ================= Pass A: layer-0 local scan (collapsed bu0) =================
#pragma unroll
    for (int p = 0; p < PP; p++) { s0r[p] = 0.f; s0i[p] = 0.f; }
#pragma unroll 1
    for (int j = 0; j < CH; j++) {
        int l = l0 + j;
        float xx = xw[l], sc = scl[l], sh = shl[l];
        float xs = xx * sc;
#pragma unroll
        for (int p = 0; p < PP; p++) {
            float bur = xs * A0r[p] + sc * B0r[p] + sh * C0r[p];
            float bui = xs * A0i[p] + sc * B0i[p] + sh * C0i[p];
            float nr = lb0r[p] * s0r[p] - lb0i[p] * s0i[p] + bur;
            float ni = lb0r[p] * s0i[p] + lb0i[p] * s0r[p] + bui;
            s0r[p] = nr; s0i[p] = ni;
        }
    }
    scan_carry(s0r, s0i, ac0r, ac0i, lane);
#pragma unroll
    for (int p = 0; p < PP; p++) { car0r[p] = s0r[p]; car0i[p] = s0i[p]; }

    // ================= Pass B: layer-0 exact + layer-1 local =================
#pragma unroll
    for (int p = 0; p < PP; p++) { s0r[p] = car0r[p]; s0i[p] = car0i[p]; s1r[p] = 0.f; s1i[p] = 0.f; }
#pragma unroll 1
    for (int j = 0; j < CH; j++) {
        int l = l0 + j;
        float xx = xw[l], sc = scl[l], sh = shl[l];
        float xs = xx * sc;
#pragma unroll
        for (int p = 0; p < PP; p++) {
            float bur = xs * A0r[p] + sc * B0r[p] + sh * C0r[p];
            float bui = xs * A0i[p] + sc * B0i[p] + sh * C0i[p];
            float nr = lb0r[p] * s0r[p] - lb0i[p] * s0i[p] + bur;
            float ni = lb0r[p] * s0i[p] + lb0i[p] * s0r[p] + bui;
            s0r[p] = nr; s0i[p] = ni;
        }
        float r0v[H];
#pragma unroll
        for (int h = 0; h < H; h++) {
            float acc = 0.f;
#pragma unroll
            for (int k = 0; k < 4; k++) {
                float4 v = c0v[h * 4 + k];
                acc += s0r[2 * k] * v.x - s0i[2 * k] * v.y + s0r[2 * k + 1] * v.z - s0i[2 * k + 1] * v.w;
            }
            float lin = xx * w1s[h] + b1s[h];
            float u0 = lin * sc + sh;
            float y0 = 2.f * acc + u0 * d0s[h];
            r0v[h] = fmaxf(y0, 0.f);
        }
        float t1r[PP], t1i[PP];
#pragma unroll
        for (int p = 0; p < PP; p++) { t1r[p] = xx * A1r[p] + B1r[p]; t1i[p] = xx * A1i[p] + B1i[p]; }
#pragma unroll
        for (int h = 0; h < H; h++) {
            float rh = r0v[h];
#pragma unroll
            for (int k = 0; k < 4; k++) {
                float4 v = bbv1[h * 4 + k];
                t1r[2 * k] += rh * v.x; t1i[2 * k] += rh * v.y;
                t1r[2 * k + 1] += rh * v.z; t1i[2 * k + 1] += rh * v.w;
            }
        }
#pragma unroll
        for (int p = 0; p < PP; p++) {
            float nr = lb1r[p] * s1r[p] - lb1i[p] * s1i[p] + t1r[p];
            float ni = lb1r[p] * s1i[p] + lb1i[p] * s1r[p] + t1i[p];
            s1r[p] = nr; s1i[p] = ni;
        }
    }
    scan_carry(s1r, s1i, ac1r, ac1i, lane);
#pragma unroll
    for (int p = 0; p < PP; p++) { car1r[p] = s1r[p]; car1i[p] = s1i[p]; }

    // ================= Pass C: layers 0,1 exact + layer-2 local + partial out =================
#pragma unroll
    for (int p = 0; p < PP; p++) {
        s0r[p] = car0r[p]; s0i[p] = car0i[p];
        s1r[p] = car1r[p]; s1i[p] = car1i[p];
        s2r[p] = 0.f;      s2i[p] = 0.f;
    }
#pragma unroll 1
    for (int j = 0; j < CH; j++) {
        int l = l0 + j;
        float xx = xw[l], sc = scl[l], sh = shl[l];
        float xs = xx * sc;
#pragma unroll
        for (int p = 0; p < PP; p++) {
            float bur = xs * A0r[p] + sc * B0r[p] + sh * C0r[p];
            float bui = xs * A0i[p] + sc * B0i[p] + sh * C0i[p];
            float nr = lb0r[p] * s0r[p] - lb0i[p] * s0i[p] + bur;
            float ni = lb0r[p] * s0i[p] + lb0i[p] * s0r[p] + bui;
            s0r[p] = nr; s0i[p] = ni;
        }
        float r0v[H], linv[H];
#pragma unroll
        for (int h = 0; h < H; h++) {
            float acc = 0.f;
#pragma unroll
            for (int k = 0; k < 4; k++) {
                float4 v = c0v[h * 4 + k];
                acc += s0r[2 * k] * v.x - s0i[2 * k] * v.y + s0r[2 * k + 1] * v.z - s0i[2 * k + 1] * v.w;
            }
            float lin = xx * w1s[h] + b1s[h];
            linv[h] = lin;
            float u0 = lin * sc + sh;
            float y0 = 2.f * acc + u0 * d0s[h];
            r0v[h] = fmaxf(y0, 0.f);
        }
        float t1r[PP], t1i[PP];
#pragma unroll
        for (int p = 0; p < PP; p++) { t1r[p] = xx * A1r[p] + B1r[p]; t1i[p] = xx * A1i[p] + B1i[p]; }
#pragma unroll
        for (int h = 0; h < H; h++) {
            float rh = r0v[h];
#pragma unroll
            for (int k = 0; k < 4; k++) {
                float4 v = bbv1[h * 4 + k];
                t1r[2 * k] += rh * v.x; t1i[2 * k] += rh * v.y;
                t1r[2 * k + 1] += rh * v.z; t1i[2 * k + 1] += rh * v.w;
            }
        }
#pragma unroll
        for (int p = 0; p < PP; p++) {
            float nr = lb1r[p] * s1r[p] - lb1i[p] * s1i[p] + t1r[p];
            float ni = lb1r[p] * s1i[p] + lb1i[p] * s1r[p] + t1i[p];
            s1r[p] = nr; s1i[p] = ni;
        }
        float rsv[H];
#pragma unroll
        for (int h = 0; h < H; h++) {
            float acc = 0.f;
#pragma unroll
            for (int k = 0; k < 4; k++) {
                float4 v = c1v[h * 4 + k];
                acc += s1r[2 * k] * v.x - s1i[2 * k] * v.y + s1r[2 * k + 1] * v.z - s1i[2 * k + 1] * v.w;
            }
            float t1h = r0v[h] + linv[h];
            float y1 = 2.f * acc + t1h * d1s[h];
            rsv[h] = r0v[h] + fmaxf(y1, 0.f);   // r0 + r1  (t2 = rsv + lin)
        }
        float t2r[PP], t2i[PP];
#pragma unroll
        for (int p = 0; p < PP; p++) { t2r[p] = xx * A2r[p] + B2r[p]; t2i[p] = xx * A2i[p] + B2i[p]; }
#pragma unroll
        for (int h = 0; h < H; h++) {
            float rh = rsv[h];
#pragma unroll
            for (int k = 0; k < 4; k++) {
                float4 v = bbv2[h * 4 + k];
                t2r[2 * k] += rh * v.x; t2i[2 * k] += rh * v.y;
                t2r[2 * k + 1] += rh * v.z; t2i[2 * k + 1] += rh * v.w;
            }
        }
#pragma unroll
        for (int p = 0; p < PP; p++) {
            float nr = lb2r[p] * s2r[p] - lb2i[p] * s2i[p] + t2r[p];
            float ni = lb2r[p] * s2i[p] + lb2i[p] * s2r[p] + t2i[p];
            s2r[p] = nr; s2i[p] = ni;
        }
        float o = b2s;
#pragma unroll
        for (int h = 0; h < H; h++) o += (rsv[h] + linv[h]) * dws[h];
        float acc2 = 0.f;
#pragma unroll
        for (int p = 0; p < PP; p++) acc2 += s2r[p] * cwr[p] - s2i[p] * cwi[p];
        pw[l] = o + 2.f * acc2;   // partial (layer-2 state assumed zero carry)
    }
    scan_carry(s2r, s2i, ac2r, ac2i, lane);  // -> carry2

    // out is linear in layer-2 carry: fix up with 2*Re(lam2^{j+1} * carry2 . cw)
    float tr[PP], ti_[PP], mr[PP], mi_[PP];
#pragma unroll
    for (int p = 0; p < PP; p++) {
        tr[p]  = cwr[p] * s2r[p] - cwi[p] * s2i[p];
        ti_[p] = cwr[p] * s2i[p] + cwi[p] * s2r[p];
        mr[p] = lb2r[p]; mi_[p] = lb2i[p];
    }
#pragma unroll 1
    for (int j = 0; j < CH; j++) {
        float corr = 0.f;
#pragma unroll
        for (int p = 0; p < PP; p++) corr += mr[p] * tr[p] - mi_[p] * ti_[p];
        pw[l0 + j] += 2.f * corr;
#pragma unroll
        for (int p = 0; p < PP; p++) {
            float t = mr[p] * lb2r[p] - mi_[p] * lb2i[p];
            mi_[p] = mr[p] * lb2i[p] + mi_[p] * lb2r[p];
            mr[p] = t;
        }
    }
    __syncthreads();
    // coalesced writeout of this wave's row
    float* orow = out + (size_t)b * SEQ;
    for (int it = 0; it < CH; ++it) {
        int i = it * 64 + lane;
        orow[i] = pw[i];
    }
}

extern "C" void kernel_launch(void* const* d_in, const int* in_sizes, int n_in,
                              void* d_out, int out_size, void* d_ws, size_t ws_size,
                              hipStream_t stream) {
    const float* x     = (const float*)d_in[0];
    const float* l1w   = (const float*)d_in[1];
    const float* l1b   = (const float*)d_in[2];
    const float* l2w   = (const float*)d_in[3];
    const float* l2b   = (const float*)d_in[4];
    const float* gam   = (const float*)d_in[5];
    const float* bet   = (const float*)d_in[6];
    const float* lamr  = (const float*)d_in[7];
    const float* lami  = (const float*)d_in[8];
    const float* bre   = (const float*)d_in[9];
    const float* bim   = (const float*)d_in[10];
    const float* cre   = (const float*)d_in[11];
    const float* cim   = (const float*)d_in[12];
    const float* dv    = (const float*)d_in[13];
    const float* lstep = (const float*)d_in[14];
    float* out = (float*)d_out;

    float* wsf     = (float*)d_ws;
    float* w_scale = wsf;
    float* w_shift = wsf + SEQ;
    float* pS      = wsf + 2 * SEQ;
    float* pQ      = pS + 16 * SEQ;

    k_stats1<<<dim3(7, 16), 256, 0, stream>>>(x, pS, pQ);
    k_stats2<<<dim3(7), 256, 0, stream>>>(pS, pQ, l1w, l1b, gam, bet, w_scale, w_shift);
    k_main<<<dim3(256), 256, 0, stream>>>(x, l1w, l1b, l2w, l2b, lamr, lami,
                                          bre, bim, cre, cim, dv, lstep,
                                          w_scale, w_shift, out);
}